// Round 3
// baseline (200.317 us; speedup 1.0000x reference)
//
#include <hip/hip_runtime.h>

#define N_NODES 50000
#define N_EDGES 800000
#define NB 196                 // buckets of 256 nodes: ceil(50000/256)
#define PBLOCKS 256            // partition blocks (== count chunks)
#define CHUNK 3125             // N_EDGES / PBLOCKS (exact)
#define GEMM_BLOCKS 782        // ceil(50000/64)

typedef unsigned short ushort_t;
typedef __attribute__((ext_vector_type(8))) short bf16x8;   // 8 bf16 = 4 VGPR
typedef __attribute__((ext_vector_type(4))) float f32x4;    // MFMA 16x16 accum

__device__ __forceinline__ float bflo(unsigned int u) {
    return __uint_as_float(u << 16);
}
__device__ __forceinline__ float bfhi(unsigned int u) {
    return __uint_as_float(u & 0xffff0000u);
}
__device__ __forceinline__ ushort_t f2bf(float f) {   // round-to-nearest-even
    unsigned int x = __float_as_uint(f);
    return (ushort_t)((x + 0x7fffu + ((x >> 16) & 1u)) >> 16);
}
__device__ __forceinline__ unsigned int pack_bf(float lo, float hi) {
    return (unsigned int)f2bf(lo) | ((unsigned int)f2bf(hi) << 16);
}
// split fp32 into bf16 hi + bf16 lo (residual); hi+lo reproduces v to ~2^-17 rel
__device__ __forceinline__ void split_bf(float v, short& hi, short& lo) {
    ushort_t h = f2bf(v);
    float r = v - __uint_as_float((unsigned int)h << 16);
    hi = (short)h;
    lo = (short)f2bf(r);
}

// ---------------- Fused: layer-1 MFMA GEMM (782 blocks) + part_count (256 blocks) ----
__global__ __launch_bounds__(256)
void gemm128_and_count(const float* __restrict__ A,
                       const float* __restrict__ B1,   // [64,64] Ws1
                       const float* __restrict__ B2,   // [64,64] Wn1
                       ushort_t* __restrict__ Cself,   // [N,64] bf16
                       ushort_t* __restrict__ Cn,      // [N,64] bf16
                       const int* __restrict__ dst,
                       int* __restrict__ blocktot) {
    __shared__ int hist[NB];

    if (blockIdx.x >= GEMM_BLOCKS) {
        // ---- part_count ----
        const int pb = blockIdx.x - GEMM_BLOCKS;
        for (int i = threadIdx.x; i < NB; i += 256) hist[i] = 0;
        __syncthreads();
        const int e0 = pb * CHUNK;
        const int e1 = e0 + CHUNK;
        for (int e = e0 + (int)threadIdx.x; e < e1; e += 256)
            atomicAdd(&hist[dst[e] >> 8], 1);
        __syncthreads();
        for (int i = threadIdx.x; i < NB; i += 256)
            blocktot[i * PBLOCKS + pb] = hist[i];
        return;
    }

    const int l  = threadIdx.x & 63;
    const int w  = threadIdx.x >> 6;     // wave 0..3
    const int lr = l & 15;
    const int lk = (l >> 4) << 3;        // 0,8,16,24

    // ---- B fragments in registers (hi/lo split), cols 32w .. 32w+31 ----
    bf16x8 bhi[2][2], blo[2][2];         // [nt][ks]
#pragma unroll
    for (int nt = 0; nt < 2; ++nt) {
        const int n = w * 32 + nt * 16 + lr;             // 0..127
        const float* Bp = (n < 64) ? (B1 + n) : (B2 + (n - 64));
#pragma unroll
        for (int ks = 0; ks < 2; ++ks) {
#pragma unroll
            for (int j = 0; j < 8; ++j) {
                float bv = Bp[(size_t)(ks * 32 + lk + j) * 64];
                short h, lo;
                split_bf(bv, h, lo);
                bhi[nt][ks][j] = h;
                blo[nt][ks][j] = lo;
            }
        }
    }

    const int m0 = blockIdx.x * 64;
    f32x4 acc[4][2];
#pragma unroll
    for (int mt = 0; mt < 4; ++mt)
#pragma unroll
        for (int nt = 0; nt < 2; ++nt) {
            f32x4 z = {0.f, 0.f, 0.f, 0.f};
            acc[mt][nt] = z;
        }

#pragma unroll
    for (int mt = 0; mt < 4; ++mt) {
        const int m = m0 + mt * 16 + lr;
        const bool valid = (m < N_NODES);
        const float* Ap = A + (size_t)m * 64 + lk;
#pragma unroll
        for (int ks = 0; ks < 2; ++ks) {
            float4 f0, f1;
            if (valid) {
                f0 = *(const float4*)(Ap + ks * 32);
                f1 = *(const float4*)(Ap + ks * 32 + 4);
            } else {
                f0 = make_float4(0.f, 0.f, 0.f, 0.f);
                f1 = f0;
            }
            const float fv[8] = {f0.x, f0.y, f0.z, f0.w, f1.x, f1.y, f1.z, f1.w};
            bf16x8 ahi, alo;
#pragma unroll
            for (int j = 0; j < 8; ++j) {
                short h, lo;
                split_bf(fv[j], h, lo);
                ahi[j] = h;
                alo[j] = lo;
            }
#pragma unroll
            for (int nt = 0; nt < 2; ++nt) {
                acc[mt][nt] = __builtin_amdgcn_mfma_f32_16x16x32_bf16(
                    ahi, bhi[nt][ks], acc[mt][nt], 0, 0, 0);
                acc[mt][nt] = __builtin_amdgcn_mfma_f32_16x16x32_bf16(
                    alo, bhi[nt][ks], acc[mt][nt], 0, 0, 0);
                acc[mt][nt] = __builtin_amdgcn_mfma_f32_16x16x32_bf16(
                    ahi, blo[nt][ks], acc[mt][nt], 0, 0, 0);
            }
        }
    }

    // ---- store: D lane col = l&15 (+tiles), rows (l>>4)*4 + r ----
#pragma unroll
    for (int mt = 0; mt < 4; ++mt) {
        const int mbase = m0 + mt * 16 + ((l >> 4) << 2);
#pragma unroll
        for (int nt = 0; nt < 2; ++nt) {
            const int n = w * 32 + nt * 16 + lr;
            ushort_t* T = (n < 64) ? (Cself + n) : (Cn + (n - 64));
#pragma unroll
            for (int r = 0; r < 4; ++r) {
                const int m = mbase + r;
                if (m < N_NODES) T[(size_t)m * 64] = f2bf(acc[mt][nt][r]);
            }
        }
    }
}

// ---------------- part_write with self-computed prefixes (no separate scan kernel) ----
// Global exclusive prefix at (bucket i, partition pb), row-major [i][pb]:
//   pre(i,pb) = sum_{i'<i} rowsum(i') + sum_{j<pb} blocktot[i][j]
// Each block computes this itself: thread t scans bucket-row t (256 values,
// L2-resident 200 KB), capturing the partial at j==pb; block-scan of row sums.
__global__ __launch_bounds__(256)
void part_write(const int* __restrict__ src, const int* __restrict__ dst,
                const int* __restrict__ blocktot, unsigned int* __restrict__ brec) {
    __shared__ int ssum[256];
    __shared__ int cur[NB];
    const int pb = blockIdx.x;           // 0..PBLOCKS-1
    const int t  = threadIdx.x;

    int rsum = 0, mypart = 0;
    if (t < NB) {
        const int* rp = blocktot + t * PBLOCKS;
#pragma unroll 8
        for (int j = 0; j < PBLOCKS; ++j) {
            if (j == pb) mypart = rsum;
            rsum += rp[j];
        }
    }
    ssum[t] = (t < NB) ? rsum : 0;
    __syncthreads();
    for (int off = 1; off < 256; off <<= 1) {
        int add = (t >= off) ? ssum[t - off] : 0;
        __syncthreads();
        ssum[t] += add;
        __syncthreads();
    }
    if (t < NB) cur[t] = (ssum[t] - rsum) + mypart;   // rowpre(t) + colpart(t)
    __syncthreads();

    const int e0 = pb * CHUNK;
    const int e1 = e0 + CHUNK;
    for (int e = e0 + t; e < e1; e += 256) {
        int d = dst[e];
        int s = src[e];
        int pos = atomicAdd(&cur[d >> 8], 1);
        brec[pos] = ((unsigned int)(d & 255) << 16) | (unsigned int)s;
    }
}

// ---------------- bucket_fill with self-computed [w0,w1) ----------------
__global__ __launch_bounds__(256)
void bucket_fill(const int* __restrict__ blocktot,
                 const unsigned int* __restrict__ brec,
                 int* __restrict__ csr_src, int* __restrict__ row_ptr) {
    __shared__ int ssum[256];
    __shared__ int cnt[256];
    __shared__ int cur[256];
    const int b = blockIdx.x;
    const int node0 = b * 256;
    const int t = threadIdx.x;

    int rsum = 0;
    if (t < NB) {
        const int* rp = blocktot + t * PBLOCKS;
#pragma unroll 8
        for (int j = 0; j < PBLOCKS; ++j) rsum += rp[j];
    }
    ssum[t] = (t < NB) ? rsum : 0;
    __syncthreads();
    for (int off = 1; off < 256; off <<= 1) {
        int add = (t >= off) ? ssum[t - off] : 0;
        __syncthreads();
        ssum[t] += add;
        __syncthreads();
    }
    const int w0 = (b == 0) ? 0 : ssum[b - 1];
    const int w1 = ssum[b];
    __syncthreads();

    cnt[t] = 0;
    __syncthreads();
    for (int i = w0 + t; i < w1; i += 256)
        atomicAdd(&cnt[brec[i] >> 16], 1);
    __syncthreads();
    const int v = cnt[t];
    cur[t] = v;
    __syncthreads();
    for (int off = 1; off < 256; off <<= 1) {
        int add = (t >= off) ? cur[t - off] : 0;
        __syncthreads();
        cur[t] += add;
        __syncthreads();
    }
    const int excl = cur[t] - v;
    const int node = node0 + t;
    if (node <= N_NODES) row_ptr[node] = w0 + excl;   // includes sentinel at node==N
    __syncthreads();
    cur[t] = w0 + excl;
    __syncthreads();
    for (int i = w0 + t; i < w1; i += 256) {
        unsigned int r = brec[i];
        int pos = atomicAdd(&cur[r >> 16], 1);
        csr_src[pos] = (int)(r & 0xffffu);
    }
}

// ---------------- Layer-1 gather + epilogue + FUSED layer-2 GEMM ----------------
// h[v] = relu( Tself1[v] + mean_{u in N(v)} Tn1[u] + b1 )   (fp32, in registers)
// Tself2[v][n] = sum_k h[k] * Ws2[k][n];  Tn2[v][n] = sum_k h[k] * Wn2[k][n]
// One wave per node (F=64, LPR=8, R=8). After the shfl_xor butterfly EVERY lane
// holds a[0..7] = neighbor-sum for cols (lane%8)*8+j, so all lanes compute the
// full epilogue o[0..7] = h slice. Lane k>>3 holds h[k] in o[k&7]; lane n
// accumulates output column n via 64 unrolled shfl+fma against a register-
// resident W2 column (wcol[64], literal-indexed).
__global__ __launch_bounds__(256)
void gather1_fused(const ushort_t* __restrict__ Tself,
                   const ushort_t* __restrict__ Tn,
                   const int* __restrict__ row_ptr,
                   const int* __restrict__ csr_src,
                   const float* __restrict__ bias,      // b1
                   const float* __restrict__ Ws2,       // [64,32]
                   const float* __restrict__ Wn2,       // [64,32]
                   ushort_t* __restrict__ Tself2,       // [N,32] bf16
                   ushort_t* __restrict__ Tn2) {        // [N,32] bf16
    constexpr int F = 64;
    constexpr int LPR = 8;
    constexpr int R = 8;
    const int lane = threadIdx.x & 63;

    // W2cat column n=lane, in registers (loads coalesce: per k, lanes 0..31 and
    // 32..63 each read one contiguous 128 B weight row segment; L2-hit after
    // the first blocks).
    float wcol[64];
    {
        const float* Wp = (lane < 32) ? (Ws2 + lane) : (Wn2 + (lane - 32));
#pragma unroll
        for (int k = 0; k < 64; ++k) wcol[k] = Wp[(size_t)k * 32];
    }

    int v = (blockIdx.x * blockDim.x + threadIdx.x) >> 6;   // node id (wave-uniform)
    if (v >= N_NODES) return;
    const int r = lane / LPR;
    const int c = lane % LPR;          // cols c*8 .. c*8+7
    int start = row_ptr[v];
    int cnt   = row_ptr[v + 1] - start;

    float a[8];
#pragma unroll
    for (int i = 0; i < 8; ++i) a[i] = 0.f;

#define ACC8(u)                                           \
    a[0] += bflo(u.x); a[1] += bfhi(u.x);                 \
    a[2] += bflo(u.y); a[3] += bfhi(u.y);                 \
    a[4] += bflo(u.z); a[5] += bfhi(u.z);                 \
    a[6] += bflo(u.w); a[7] += bfhi(u.w);

    int t = r;
    for (; t + 3 * R < cnt; t += 4 * R) {
        int s0 = csr_src[start + t];
        int s1 = csr_src[start + t + R];
        int s2 = csr_src[start + t + 2 * R];
        int s3 = csr_src[start + t + 3 * R];
        uint4 u0 = *(const uint4*)&Tn[(size_t)s0 * F + c * 8];
        uint4 u1 = *(const uint4*)&Tn[(size_t)s1 * F + c * 8];
        uint4 u2 = *(const uint4*)&Tn[(size_t)s2 * F + c * 8];
        uint4 u3 = *(const uint4*)&Tn[(size_t)s3 * F + c * 8];
        ACC8(u0) ACC8(u1) ACC8(u2) ACC8(u3)
    }
    if (t + R < cnt) {
        int s0 = csr_src[start + t];
        int s1 = csr_src[start + t + R];
        uint4 u0 = *(const uint4*)&Tn[(size_t)s0 * F + c * 8];
        uint4 u1 = *(const uint4*)&Tn[(size_t)s1 * F + c * 8];
        ACC8(u0) ACC8(u1)
        t += 2 * R;
    }
    if (t < cnt) {
        int s = csr_src[start + t];
        uint4 u = *(const uint4*)&Tn[(size_t)s * F + c * 8];
        ACC8(u)
    }
#undef ACC8

#pragma unroll
    for (int off = LPR; off < 64; off <<= 1) {
#pragma unroll
        for (int i = 0; i < 8; ++i) a[i] += __shfl_xor(a[i], off);
    }

    // ---- epilogue on ALL lanes (fp32 h slice, post-relu) ----
    const float inv = 1.0f / (float)max(cnt, 1);
    uint4 su = *(const uint4*)&Tself[(size_t)v * F + c * 8];
    float4 bA = *(const float4*)&bias[c * 8];
    float4 bB = *(const float4*)&bias[c * 8 + 4];
    float o[8];
    o[0] = bflo(su.x) + a[0] * inv + bA.x;
    o[1] = bfhi(su.x) + a[1] * inv + bA.y;
    o[2] = bflo(su.y) + a[2] * inv + bA.z;
    o[3] = bfhi(su.y) + a[3] * inv + bA.w;
    o[4] = bflo(su.z) + a[4] * inv + bB.x;
    o[5] = bfhi(su.z) + a[5] * inv + bB.y;
    o[6] = bflo(su.w) + a[6] * inv + bB.z;
    o[7] = bfhi(su.w) + a[7] * inv + bB.w;
#pragma unroll
    for (int i = 0; i < 8; ++i) o[i] = fmaxf(o[i], 0.f);

    // ---- fused layer-2: out column n = lane; h[k] lives in o[k&7] of lane k>>3 ----
    float o2 = 0.f;
#pragma unroll
    for (int k = 0; k < 64; ++k)
        o2 = fmaf(__shfl(o[k & 7], k >> 3), wcol[k], o2);

    if (lane < 32) Tself2[(size_t)v * 32 + lane] = f2bf(o2);
    else           Tn2[(size_t)v * 32 + (lane - 32)] = f2bf(o2);
}

// ---------------- Layer-2 gather + epilogue (unchanged) ----------------
template <int F, bool RELU, bool OBF16>
__global__ __launch_bounds__(256)
void gather_epilogue(const ushort_t* __restrict__ Tself,
                     const ushort_t* __restrict__ Tn,
                     const int* __restrict__ row_ptr,
                     const int* __restrict__ csr_src, const float* __restrict__ bias,
                     void* __restrict__ outv) {
    constexpr int LPR = F / 8;
    constexpr int R   = 64 / LPR;
    int v = (blockIdx.x * blockDim.x + threadIdx.x) >> 6;   // node id
    int lane = threadIdx.x & 63;
    int r = lane / LPR;
    int c = lane % LPR;          // handles cols c*8 .. c*8+7
    if (v >= N_NODES) return;
    int start = row_ptr[v];
    int cnt   = row_ptr[v + 1] - start;

    float a[8];
#pragma unroll
    for (int i = 0; i < 8; ++i) a[i] = 0.f;

#define ACC8(u)                                           \
    a[0] += bflo(u.x); a[1] += bfhi(u.x);                 \
    a[2] += bflo(u.y); a[3] += bfhi(u.y);                 \
    a[4] += bflo(u.z); a[5] += bfhi(u.z);                 \
    a[6] += bflo(u.w); a[7] += bfhi(u.w);

    int t = r;
    for (; t + 3 * R < cnt; t += 4 * R) {
        int s0 = csr_src[start + t];
        int s1 = csr_src[start + t + R];
        int s2 = csr_src[start + t + 2 * R];
        int s3 = csr_src[start + t + 3 * R];
        uint4 u0 = *(const uint4*)&Tn[(size_t)s0 * F + c * 8];
        uint4 u1 = *(const uint4*)&Tn[(size_t)s1 * F + c * 8];
        uint4 u2 = *(const uint4*)&Tn[(size_t)s2 * F + c * 8];
        uint4 u3 = *(const uint4*)&Tn[(size_t)s3 * F + c * 8];
        ACC8(u0) ACC8(u1) ACC8(u2) ACC8(u3)
    }
    if (t + R < cnt) {
        int s0 = csr_src[start + t];
        int s1 = csr_src[start + t + R];
        uint4 u0 = *(const uint4*)&Tn[(size_t)s0 * F + c * 8];
        uint4 u1 = *(const uint4*)&Tn[(size_t)s1 * F + c * 8];
        ACC8(u0) ACC8(u1)
        t += 2 * R;
    }
    if (t < cnt) {
        int s = csr_src[start + t];
        uint4 u = *(const uint4*)&Tn[(size_t)s * F + c * 8];
        ACC8(u)
    }
#undef ACC8

#pragma unroll
    for (int off = LPR; off < 64; off <<= 1) {
#pragma unroll
        for (int i = 0; i < 8; ++i) a[i] += __shfl_xor(a[i], off);
    }

    if (r == 0) {
        const float inv = 1.0f / (float)max(cnt, 1);
        uint4 su = *(const uint4*)&Tself[(size_t)v * F + c * 8];
        float4 bA = *(const float4*)&bias[c * 8];
        float4 bB = *(const float4*)&bias[c * 8 + 4];
        float o[8];
        o[0] = bflo(su.x) + a[0] * inv + bA.x;
        o[1] = bfhi(su.x) + a[1] * inv + bA.y;
        o[2] = bflo(su.y) + a[2] * inv + bA.z;
        o[3] = bfhi(su.y) + a[3] * inv + bA.w;
        o[4] = bflo(su.z) + a[4] * inv + bB.x;
        o[5] = bfhi(su.z) + a[5] * inv + bB.y;
        o[6] = bflo(su.w) + a[6] * inv + bB.z;
        o[7] = bfhi(su.w) + a[7] * inv + bB.w;
        if (RELU) {
#pragma unroll
            for (int i = 0; i < 8; ++i) o[i] = fmaxf(o[i], 0.f);
        }
        if (OBF16) {
            ushort_t* out = (ushort_t*)outv;
            uint4 p;
            p.x = pack_bf(o[0], o[1]); p.y = pack_bf(o[2], o[3]);
            p.z = pack_bf(o[4], o[5]); p.w = pack_bf(o[6], o[7]);
            *(uint4*)&out[(size_t)v * F + c * 8] = p;
        } else {
            float* out = (float*)outv;
            *(float4*)&out[(size_t)v * F + c * 8]     = make_float4(o[0], o[1], o[2], o[3]);
            *(float4*)&out[(size_t)v * F + c * 8 + 4] = make_float4(o[4], o[5], o[6], o[7]);
        }
    }
}

extern "C" void kernel_launch(void* const* d_in, const int* in_sizes, int n_in,
                              void* d_out, int out_size, void* d_ws, size_t ws_size,
                              hipStream_t stream) {
    const float* features = (const float*)d_in[0];
    const float* W_self1  = (const float*)d_in[1];
    const float* W_neigh1 = (const float*)d_in[2];
    const float* b1       = (const float*)d_in[3];
    const float* W_self2  = (const float*)d_in[4];
    const float* W_neigh2 = (const float*)d_in[5];
    const float* b2       = (const float*)d_in[6];
    const int*   src      = (const int*)d_in[7];
    const int*   dst      = (const int*)d_in[8];

    // Workspace:
    //   Tself1 : N*64 bf16 (6.4 MB)
    //   Tn1    : N*64 bf16 (6.4 MB)
    //   T2     : N*64 bf16 (6.4 MB) = Tself2 (N*32) | Tn2 (N*32)  (old h slot;
    //            separate from Tself1 because gather1_fused reads Tself1/Tn1
    //            while writing T2)
    //   row_ptr: N+1; csr_src: E; brec: E; blocktot: NB*PBLOCKS
    ushort_t* Tself1 = (ushort_t*)d_ws;
    ushort_t* Tn1    = Tself1 + (size_t)N_NODES * 64;
    ushort_t* T2     = Tn1 + (size_t)N_NODES * 64;
    int* row_ptr     = (int*)(T2 + (size_t)N_NODES * 64);
    int* csr_src     = row_ptr + (N_NODES + 1);
    unsigned int* brec = (unsigned int*)(csr_src + N_EDGES);
    int* blocktot    = (int*)(brec + N_EDGES);

    ushort_t* Tself2 = T2;
    ushort_t* Tn2    = T2 + (size_t)N_NODES * 32;

    const int gather_blocks = (N_NODES + 3) / 4;     // 12500 (4 waves/block)

    // ---- 1: layer-1 MFMA GEMM overlapped with CSR count ----
    gemm128_and_count<<<GEMM_BLOCKS + PBLOCKS, 256, 0, stream>>>(
        features, W_self1, W_neigh1, Tself1, Tn1, dst, blocktot);
    // ---- 2: radix partition write (self-computed prefixes, no scan kernel) ----
    part_write<<<PBLOCKS, 256, 0, stream>>>(src, dst, blocktot, brec);
    // ---- 3: bucket fill -> csr_src, row_ptr ----
    bucket_fill<<<NB, 256, 0, stream>>>(blocktot, brec, csr_src, row_ptr);
    // ---- 4: layer-1 gather + epilogue + fused layer-2 GEMM -> Tself2/Tn2 ----
    gather1_fused<<<gather_blocks, 256, 0, stream>>>(
        Tself1, Tn1, row_ptr, csr_src, b1, W_self2, W_neigh2, Tself2, Tn2);
    // ---- 5: layer-2 gather + epilogue -> out (fp32) ----
    gather_epilogue<32, false, false><<<gather_blocks, 256, 0, stream>>>(
        Tself2, Tn2, row_ptr, csr_src, b2, d_out);
}

// Round 4
// 164.345 us; speedup vs baseline: 1.2189x; 1.2189x over previous
//
#include <hip/hip_runtime.h>

#define N_NODES 50000
#define N_EDGES 800000
#define NB 196                 // buckets of 256 nodes: ceil(50000/256)
#define PBLOCKS 256            // partition blocks (== count chunks)
#define CHUNK 3125             // N_EDGES / PBLOCKS (exact)
#define GEMM_BLOCKS 782        // ceil(50000/64)

typedef unsigned short ushort_t;
typedef __attribute__((ext_vector_type(8))) short bf16x8;   // 8 bf16 = 4 VGPR
typedef __attribute__((ext_vector_type(4))) float f32x4;    // MFMA 16x16 accum

__device__ __forceinline__ float bflo(unsigned int u) {
    return __uint_as_float(u << 16);
}
__device__ __forceinline__ float bfhi(unsigned int u) {
    return __uint_as_float(u & 0xffff0000u);
}
__device__ __forceinline__ ushort_t f2bf(float f) {   // round-to-nearest-even
    unsigned int x = __float_as_uint(f);
    return (ushort_t)((x + 0x7fffu + ((x >> 16) & 1u)) >> 16);
}
__device__ __forceinline__ unsigned int pack_bf(float lo, float hi) {
    return (unsigned int)f2bf(lo) | ((unsigned int)f2bf(hi) << 16);
}
// split fp32 into bf16 hi + bf16 lo (residual); hi+lo reproduces v to ~2^-17 rel
__device__ __forceinline__ void split_bf(float v, short& hi, short& lo) {
    ushort_t h = f2bf(v);
    float r = v - __uint_as_float((unsigned int)h << 16);
    hi = (short)h;
    lo = (short)f2bf(r);
}

// ---------------- Fused: layer-1 MFMA GEMM (782 blocks) + part_count (256 blocks) ----
__global__ __launch_bounds__(256)
void gemm128_and_count(const float* __restrict__ A,
                       const float* __restrict__ B1,   // [64,64] Ws1
                       const float* __restrict__ B2,   // [64,64] Wn1
                       ushort_t* __restrict__ Cself,   // [N,64] bf16
                       ushort_t* __restrict__ Cn,      // [N,64] bf16
                       const int* __restrict__ dst,
                       int* __restrict__ blocktot) {
    __shared__ int hist[NB];

    if (blockIdx.x >= GEMM_BLOCKS) {
        // ---- part_count ----
        const int pb = blockIdx.x - GEMM_BLOCKS;
        for (int i = threadIdx.x; i < NB; i += 256) hist[i] = 0;
        __syncthreads();
        const int e0 = pb * CHUNK;
        const int e1 = e0 + CHUNK;
        for (int e = e0 + (int)threadIdx.x; e < e1; e += 256)
            atomicAdd(&hist[dst[e] >> 8], 1);
        __syncthreads();
        for (int i = threadIdx.x; i < NB; i += 256)
            blocktot[i * PBLOCKS + pb] = hist[i];
        return;
    }

    const int l  = threadIdx.x & 63;
    const int w  = threadIdx.x >> 6;     // wave 0..3
    const int lr = l & 15;
    const int lk = (l >> 4) << 3;        // 0,8,16,24

    // ---- B fragments in registers (hi/lo split), cols 32w .. 32w+31 ----
    bf16x8 bhi[2][2], blo[2][2];         // [nt][ks]
#pragma unroll
    for (int nt = 0; nt < 2; ++nt) {
        const int n = w * 32 + nt * 16 + lr;             // 0..127
        const float* Bp = (n < 64) ? (B1 + n) : (B2 + (n - 64));
#pragma unroll
        for (int ks = 0; ks < 2; ++ks) {
#pragma unroll
            for (int j = 0; j < 8; ++j) {
                float bv = Bp[(size_t)(ks * 32 + lk + j) * 64];
                short h, lo;
                split_bf(bv, h, lo);
                bhi[nt][ks][j] = h;
                blo[nt][ks][j] = lo;
            }
        }
    }

    const int m0 = blockIdx.x * 64;
    f32x4 acc[4][2];
#pragma unroll
    for (int mt = 0; mt < 4; ++mt)
#pragma unroll
        for (int nt = 0; nt < 2; ++nt) {
            f32x4 z = {0.f, 0.f, 0.f, 0.f};
            acc[mt][nt] = z;
        }

#pragma unroll
    for (int mt = 0; mt < 4; ++mt) {
        const int m = m0 + mt * 16 + lr;
        const bool valid = (m < N_NODES);
        const float* Ap = A + (size_t)m * 64 + lk;
#pragma unroll
        for (int ks = 0; ks < 2; ++ks) {
            float4 f0, f1;
            if (valid) {
                f0 = *(const float4*)(Ap + ks * 32);
                f1 = *(const float4*)(Ap + ks * 32 + 4);
            } else {
                f0 = make_float4(0.f, 0.f, 0.f, 0.f);
                f1 = f0;
            }
            const float fv[8] = {f0.x, f0.y, f0.z, f0.w, f1.x, f1.y, f1.z, f1.w};
            bf16x8 ahi, alo;
#pragma unroll
            for (int j = 0; j < 8; ++j) {
                short h, lo;
                split_bf(fv[j], h, lo);
                ahi[j] = h;
                alo[j] = lo;
            }
#pragma unroll
            for (int nt = 0; nt < 2; ++nt) {
                acc[mt][nt] = __builtin_amdgcn_mfma_f32_16x16x32_bf16(
                    ahi, bhi[nt][ks], acc[mt][nt], 0, 0, 0);
                acc[mt][nt] = __builtin_amdgcn_mfma_f32_16x16x32_bf16(
                    alo, bhi[nt][ks], acc[mt][nt], 0, 0, 0);
                acc[mt][nt] = __builtin_amdgcn_mfma_f32_16x16x32_bf16(
                    ahi, blo[nt][ks], acc[mt][nt], 0, 0, 0);
            }
        }
    }

    // ---- store: D lane col = l&15 (+tiles), rows (l>>4)*4 + r ----
#pragma unroll
    for (int mt = 0; mt < 4; ++mt) {
        const int mbase = m0 + mt * 16 + ((l >> 4) << 2);
#pragma unroll
        for (int nt = 0; nt < 2; ++nt) {
            const int n = w * 32 + nt * 16 + lr;
            ushort_t* T = (n < 64) ? (Cself + n) : (Cn + (n - 64));
#pragma unroll
            for (int r = 0; r < 4; ++r) {
                const int m = mbase + r;
                if (m < N_NODES) T[(size_t)m * 64] = f2bf(acc[mt][nt][r]);
            }
        }
    }
}

// ---------------- part_write with self-computed prefixes (no separate scan kernel) ----
__global__ __launch_bounds__(256)
void part_write(const int* __restrict__ src, const int* __restrict__ dst,
                const int* __restrict__ blocktot, unsigned int* __restrict__ brec) {
    __shared__ int ssum[256];
    __shared__ int cur[NB];
    const int pb = blockIdx.x;           // 0..PBLOCKS-1
    const int t  = threadIdx.x;

    int rsum = 0, mypart = 0;
    if (t < NB) {
        const int* rp = blocktot + t * PBLOCKS;
#pragma unroll 8
        for (int j = 0; j < PBLOCKS; ++j) {
            if (j == pb) mypart = rsum;
            rsum += rp[j];
        }
    }
    ssum[t] = (t < NB) ? rsum : 0;
    __syncthreads();
    for (int off = 1; off < 256; off <<= 1) {
        int add = (t >= off) ? ssum[t - off] : 0;
        __syncthreads();
        ssum[t] += add;
        __syncthreads();
    }
    if (t < NB) cur[t] = (ssum[t] - rsum) + mypart;   // rowpre(t) + colpart(t)
    __syncthreads();

    const int e0 = pb * CHUNK;
    const int e1 = e0 + CHUNK;
    for (int e = e0 + t; e < e1; e += 256) {
        int d = dst[e];
        int s = src[e];
        int pos = atomicAdd(&cur[d >> 8], 1);
        brec[pos] = ((unsigned int)(d & 255) << 16) | (unsigned int)s;
    }
}

// ---------------- bucket_fill with self-computed [w0,w1) ----------------
__global__ __launch_bounds__(256)
void bucket_fill(const int* __restrict__ blocktot,
                 const unsigned int* __restrict__ brec,
                 int* __restrict__ csr_src, int* __restrict__ row_ptr) {
    __shared__ int ssum[256];
    __shared__ int cnt[256];
    __shared__ int cur[256];
    const int b = blockIdx.x;
    const int node0 = b * 256;
    const int t = threadIdx.x;

    int rsum = 0;
    if (t < NB) {
        const int* rp = blocktot + t * PBLOCKS;
#pragma unroll 8
        for (int j = 0; j < PBLOCKS; ++j) rsum += rp[j];
    }
    ssum[t] = (t < NB) ? rsum : 0;
    __syncthreads();
    for (int off = 1; off < 256; off <<= 1) {
        int add = (t >= off) ? ssum[t - off] : 0;
        __syncthreads();
        ssum[t] += add;
        __syncthreads();
    }
    const int w0 = (b == 0) ? 0 : ssum[b - 1];
    const int w1 = ssum[b];
    __syncthreads();

    cnt[t] = 0;
    __syncthreads();
    for (int i = w0 + t; i < w1; i += 256)
        atomicAdd(&cnt[brec[i] >> 16], 1);
    __syncthreads();
    const int v = cnt[t];
    cur[t] = v;
    __syncthreads();
    for (int off = 1; off < 256; off <<= 1) {
        int add = (t >= off) ? cur[t - off] : 0;
        __syncthreads();
        cur[t] += add;
        __syncthreads();
    }
    const int excl = cur[t] - v;
    const int node = node0 + t;
    if (node <= N_NODES) row_ptr[node] = w0 + excl;   // includes sentinel at node==N
    __syncthreads();
    cur[t] = w0 + excl;
    __syncthreads();
    for (int i = w0 + t; i < w1; i += 256) {
        unsigned int r = brec[i];
        int pos = atomicAdd(&cur[r >> 16], 1);
        csr_src[pos] = (int)(r & 0xffffu);
    }
}

// ---------------- Layer-2 MFMA GEMM: A bf16 [N,64]; C = A x [Ws2 | Wn2] ----------------
__global__ __launch_bounds__(256)
void gemm_cat64_bf16(const ushort_t* __restrict__ A,
                     const float* __restrict__ B1,   // [64,32] Ws2
                     const float* __restrict__ B2,   // [64,32] Wn2
                     ushort_t* __restrict__ Cself,   // [N,32] bf16
                     ushort_t* __restrict__ Cn) {    // [N,32] bf16
    const int l  = threadIdx.x & 63;
    const int w  = threadIdx.x >> 6;
    const int lr = l & 15;
    const int lk = (l >> 4) << 3;

    const int n = w * 16 + lr;                        // 0..63
    const float* Bp = (n < 32) ? (B1 + n) : (B2 + (n - 32));
    bf16x8 bhi[2], blo[2];                            // [ks]
#pragma unroll
    for (int ks = 0; ks < 2; ++ks) {
#pragma unroll
        for (int j = 0; j < 8; ++j) {
            float bv = Bp[(size_t)(ks * 32 + lk + j) * 32];
            short h, lo;
            split_bf(bv, h, lo);
            bhi[ks][j] = h;
            blo[ks][j] = lo;
        }
    }

    const int m0 = blockIdx.x * 64;
    f32x4 acc[4];
#pragma unroll
    for (int mt = 0; mt < 4; ++mt) {
        f32x4 z = {0.f, 0.f, 0.f, 0.f};
        acc[mt] = z;
    }

#pragma unroll
    for (int mt = 0; mt < 4; ++mt) {
        const int m = m0 + mt * 16 + lr;
        const bool valid = (m < N_NODES);
#pragma unroll
        for (int ks = 0; ks < 2; ++ks) {
            bf16x8 a;
            if (valid) {
                a = *(const bf16x8*)&A[(size_t)m * 64 + ks * 32 + lk];
            } else {
                bf16x8 z = {0, 0, 0, 0, 0, 0, 0, 0};
                a = z;
            }
            acc[mt] = __builtin_amdgcn_mfma_f32_16x16x32_bf16(a, bhi[ks], acc[mt], 0, 0, 0);
            acc[mt] = __builtin_amdgcn_mfma_f32_16x16x32_bf16(a, blo[ks], acc[mt], 0, 0, 0);
        }
    }

    ushort_t* T = (n < 32) ? (Cself + n) : (Cn + (n - 32));
#pragma unroll
    for (int mt = 0; mt < 4; ++mt) {
        const int mbase = m0 + mt * 16 + ((l >> 4) << 2);
#pragma unroll
        for (int r = 0; r < 4; ++r) {
            const int m = mbase + r;
            if (m < N_NODES) T[(size_t)m * 32] = f2bf(acc[mt][r]);
        }
    }
}

// ---------------- Gather mean + fused epilogue, MLP-optimized ----------------
// 2 nodes per wave (32 lanes each). Per node:
//   one coalesced index load (lanes 0..cnt-1 of the half read csr_src[start+hl]),
//   indices broadcast via shfl, then ALL row loads issued back-to-back under
//   exec masks (up to MAXJ per lane in flight) before a single wait.
// Fast path covers cnt<=32 (mean degree 16, P(cnt>32)~3e-5); rare tail loops.
template <int F, bool RELU, bool OBF16>
__global__ __launch_bounds__(256)
void gather_epilogue(const ushort_t* __restrict__ Tself,
                     const ushort_t* __restrict__ Tn,
                     const int* __restrict__ row_ptr,
                     const int* __restrict__ csr_src, const float* __restrict__ bias,
                     void* __restrict__ outv) {
    constexpr int LPR  = F / 8;      // lanes per row: 8 (F=64) / 4 (F=32)
    constexpr int G    = 32 / LPR;   // row-groups per node: 4 / 8
    constexpr int MAXJ = 32 / G;     // max fast-path rows per group: 8 / 4
    const int lane = threadIdx.x & 63;
    const int half = lane >> 5;      // node slot within wave
    const int hl   = lane & 31;
    const int r = hl / LPR;          // row-group
    const int c = hl % LPR;          // cols c*8 .. c*8+7
    const int v = (((int)blockIdx.x * (int)blockDim.x + (int)threadIdx.x) >> 6) * 2 + half;
    if (v >= N_NODES) return;
    const int start = row_ptr[v];
    const int cnt   = row_ptr[v + 1] - start;

    float a[8];
#pragma unroll
    for (int i = 0; i < 8; ++i) a[i] = 0.f;

#define ACC8(u)                                           \
    a[0] += bflo(u.x); a[1] += bfhi(u.x);                 \
    a[2] += bflo(u.y); a[3] += bfhi(u.y);                 \
    a[4] += bflo(u.z); a[5] += bfhi(u.z);                 \
    a[6] += bflo(u.w); a[7] += bfhi(u.w);

    // ---- coalesced index load: one int per lane of this half ----
    int idx = 0;
    if (hl < cnt) idx = csr_src[start + hl];

    const int nfast = (cnt < 32) ? cnt : 32;
    int  sidx[MAXJ];
    bool act[MAXJ];
#pragma unroll
    for (int j = 0; j < MAXJ; ++j) {
        const int t = r + j * G;
        act[j]  = (t < nfast);
        sidx[j] = __shfl(idx, half * 32 + t);
    }
    uint4 u[MAXJ];
#pragma unroll
    for (int j = 0; j < MAXJ; ++j) {
        u[j] = make_uint4(0u, 0u, 0u, 0u);
        if (act[j]) u[j] = *(const uint4*)&Tn[(size_t)sidx[j] * F + c * 8];
    }
#pragma unroll
    for (int j = 0; j < MAXJ; ++j) { ACC8(u[j]) }   // zeros for inactive slots

    // ---- rare tail: cnt > 32 ----
    for (int t = 32 + r; t < cnt; t += G) {
        const int s = csr_src[start + t];
        uint4 uu = *(const uint4*)&Tn[(size_t)s * F + c * 8];
        ACC8(uu)
    }
#undef ACC8

    // ---- reduce across row-groups (within the 32-lane half) ----
#pragma unroll
    for (int off = LPR; off < 32; off <<= 1) {
#pragma unroll
        for (int i = 0; i < 8; ++i) a[i] += __shfl_xor(a[i], off);
    }

    if (r == 0) {
        const float inv = 1.0f / (float)max(cnt, 1);
        uint4 su = *(const uint4*)&Tself[(size_t)v * F + c * 8];
        float4 bA = *(const float4*)&bias[c * 8];
        float4 bB = *(const float4*)&bias[c * 8 + 4];
        float o[8];
        o[0] = bflo(su.x) + a[0] * inv + bA.x;
        o[1] = bfhi(su.x) + a[1] * inv + bA.y;
        o[2] = bflo(su.y) + a[2] * inv + bA.z;
        o[3] = bfhi(su.y) + a[3] * inv + bA.w;
        o[4] = bflo(su.z) + a[4] * inv + bB.x;
        o[5] = bfhi(su.z) + a[5] * inv + bB.y;
        o[6] = bflo(su.w) + a[6] * inv + bB.z;
        o[7] = bfhi(su.w) + a[7] * inv + bB.w;
        if (RELU) {
#pragma unroll
            for (int i = 0; i < 8; ++i) o[i] = fmaxf(o[i], 0.f);
        }
        if (OBF16) {
            ushort_t* out = (ushort_t*)outv;
            uint4 p;
            p.x = pack_bf(o[0], o[1]); p.y = pack_bf(o[2], o[3]);
            p.z = pack_bf(o[4], o[5]); p.w = pack_bf(o[6], o[7]);
            *(uint4*)&out[(size_t)v * F + c * 8] = p;
        } else {
            float* out = (float*)outv;
            *(float4*)&out[(size_t)v * F + c * 8]     = make_float4(o[0], o[1], o[2], o[3]);
            *(float4*)&out[(size_t)v * F + c * 8 + 4] = make_float4(o[4], o[5], o[6], o[7]);
        }
    }
}

extern "C" void kernel_launch(void* const* d_in, const int* in_sizes, int n_in,
                              void* d_out, int out_size, void* d_ws, size_t ws_size,
                              hipStream_t stream) {
    const float* features = (const float*)d_in[0];
    const float* W_self1  = (const float*)d_in[1];
    const float* W_neigh1 = (const float*)d_in[2];
    const float* b1       = (const float*)d_in[3];
    const float* W_self2  = (const float*)d_in[4];
    const float* W_neigh2 = (const float*)d_in[5];
    const float* b2       = (const float*)d_in[6];
    const int*   src      = (const int*)d_in[7];
    const int*   dst      = (const int*)d_in[8];

    // Workspace:
    //   Tself1 : N*64 bf16 (6.4 MB)  -- reused as Tself2+Tn2 (N*32 each) after gather1
    //   Tn1    : N*64 bf16 (6.4 MB)
    //   h      : N*64 bf16 (6.4 MB)
    //   row_ptr: N+1; csr_src: E; brec: E; blocktot: NB*PBLOCKS
    ushort_t* Tself1 = (ushort_t*)d_ws;
    ushort_t* Tn1    = Tself1 + (size_t)N_NODES * 64;
    ushort_t* h      = Tn1 + (size_t)N_NODES * 64;
    int* row_ptr     = (int*)(h + (size_t)N_NODES * 64);
    int* csr_src     = row_ptr + (N_NODES + 1);
    unsigned int* brec = (unsigned int*)(csr_src + N_EDGES);
    int* blocktot    = (int*)(brec + N_EDGES);

    ushort_t* Tself2 = Tself1;                       // N*32, reuse (dead after gather1)
    ushort_t* Tn2    = Tself1 + (size_t)N_NODES * 32;

    const int gather_blocks = (N_NODES + 7) / 8;     // 6250 (4 waves x 2 nodes/block)

    // ---- 1: layer-1 MFMA GEMM overlapped with CSR count ----
    gemm128_and_count<<<GEMM_BLOCKS + PBLOCKS, 256, 0, stream>>>(
        features, W_self1, W_neigh1, Tself1, Tn1, dst, blocktot);
    // ---- 2: radix partition write (self-computed prefixes, no scan kernel) ----
    part_write<<<PBLOCKS, 256, 0, stream>>>(src, dst, blocktot, brec);
    // ---- 3: bucket fill -> csr_src, row_ptr ----
    bucket_fill<<<NB, 256, 0, stream>>>(blocktot, brec, csr_src, row_ptr);
    // ---- 4: layer-1 gather + epilogue -> h (bf16) ----
    gather_epilogue<64, true, true><<<gather_blocks, 256, 0, stream>>>(
        Tself1, Tn1, row_ptr, csr_src, b1, h);
    // ---- 5: layer-2 MFMA GEMM (bf16 A) ----
    gemm_cat64_bf16<<<GEMM_BLOCKS, 256, 0, stream>>>(h, W_self2, W_neigh2, Tself2, Tn2);
    // ---- 6: layer-2 gather + epilogue -> out (fp32) ----
    gather_epilogue<32, false, false><<<gather_blocks, 256, 0, stream>>>(
        Tself2, Tn2, row_ptr, csr_src, b2, d_out);
}